// Round 17
// baseline (331.803 us; speedup 1.0000x reference)
//
#include <hip/hip_runtime.h>
#include <hip/hip_fp16.h>
#include <cstdint>

#define DH 64
#define EPSV 1e-5f
#define GBLK 2048
#define NBUK 256
#define BROWS 512
#define BINJ 8
#define CAP 12288

typedef _Float16 half8 __attribute__((ext_vector_type(8)));
typedef float f32x4 __attribute__((ext_vector_type(4)));

// Combined setup: graph boundaries + bucket cursors + 3x W transpose->fp16
__global__ __launch_bounds__(256) void k_setup(
    const int* __restrict__ batch, int* __restrict__ gstart,
    unsigned* __restrict__ gcur0,
    const float* __restrict__ w0, const float* __restrict__ w1,
    const float* __restrict__ w2, unsigned short* __restrict__ wt0,
    unsigned short* __restrict__ wt1, unsigned short* __restrict__ wt2,
    int N_, int G_, int DIN_, int nbN) {
  const int b = blockIdx.x, t = threadIdx.x;
  if (b < nbN) {
    int i = b * 256 + t;
    if (i >= N_) return;
    int bb = batch[i];
    if (i == 0) {
      for (int g = 0; g <= bb; ++g) gstart[g] = 0;
    }
    int nb2 = (i + 1 < N_) ? batch[i + 1] : G_;
    for (int g = bb + 1; g <= nb2; ++g) gstart[g] = i + 1;
  } else if (b == nbN) {
    if (t < NBUK) gcur0[t] = (unsigned)(t * CAP);
  } else {
    int idx = (b - nbN - 1) * 256 + t;
    if (idx < 64 * 128) {
      int c = idx / 128, k = idx % 128;
      wt0[idx] = __half_as_ushort(__float2half(k < DIN_ ? w0[k * DH + c] : 0.f));
    } else if (idx < 64 * 128 + 64 * 64) {
      int l2 = idx - 64 * 128;
      int c = l2 / 64, k = l2 % 64;
      wt1[l2] = __half_as_ushort(__float2half(w1[k * DH + c]));
    } else if (idx < 64 * 128 + 2 * 64 * 64) {
      int l2 = idx - 64 * 128 - 64 * 64;
      int c = l2 / 64, k = l2 % 64;
      wt2[l2] = __half_as_ushort(__float2half(w2[k * DH + c]));
    }
  }
}

// Pass 1: bin edges by dst bucket. payload: hi=(dst&511)<<17|src, lo=fp32 ew.
__global__ __launch_bounds__(256) void k_bin0(
    const int* __restrict__ src, const int* __restrict__ dst,
    const float* __restrict__ ew, unsigned* __restrict__ gcur0,
    unsigned long long* __restrict__ bstage, int E_) {
  __shared__ unsigned cntL[NBUK], offL[NBUK], runL[NBUK];
  const int t = threadIdx.x;
  const int base = blockIdx.x * (256 * BINJ);
  cntL[t] = 0;
  runL[t] = 0;
  __syncthreads();
  unsigned hi[BINJ], lo[BINJ];
  int bb[BINJ];
#pragma unroll
  for (int j = 0; j < BINJ; ++j) {
    int e = base + j * 256 + t;
    bb[j] = -1;
    if (e < E_) {
      int q = dst[e];
      hi[j] = ((unsigned)(q & (BROWS - 1)) << 17) | (unsigned)src[e];
      lo[j] = __float_as_uint(ew[e]);
      bb[j] = q >> 9;
      atomicAdd(&cntL[bb[j]], 1u);
    }
  }
  __syncthreads();
  offL[t] = cntL[t] ? atomicAdd(&gcur0[t], cntL[t]) : 0u;
  __syncthreads();
#pragma unroll
  for (int j = 0; j < BINJ; ++j) {
    if (bb[j] >= 0) {
      unsigned p = offL[bb[j]] + atomicAdd(&runL[bb[j]], 1u);
      bstage[p] = ((unsigned long long)hi[j] << 32) | lo[j];
    }
  }
}

// Per-bucket histogram from staged runs (deterministic fixed-point sum).
__global__ __launch_bounds__(256) void k_bcnt(
    const unsigned long long* __restrict__ bstage, const unsigned* __restrict__ gcur0,
    int* __restrict__ cnt, float* __restrict__ dinv, float* __restrict__ sc, int N_) {
  __shared__ unsigned cntL[BROWS], degL[BROWS];
  const int b = blockIdx.x, t = threadIdx.x;
  for (int i = t; i < BROWS; i += 256) {
    cntL[i] = 0;
    degL[i] = 0;
  }
  __syncthreads();
  const unsigned beg = (unsigned)(b * CAP), end = gcur0[b];
  for (unsigned p = beg + t; p < end; p += 256) {
    unsigned long long v = bstage[p];
    unsigned r = (unsigned)(v >> 49);
    float w = __uint_as_float((unsigned)v);
    atomicAdd(&cntL[r], 1u);
    atomicAdd(&degL[r], (unsigned)(w * 16777216.0f));
  }
  __syncthreads();
  for (int i = t; i < BROWS; i += 256) {
    int r = b * BROWS + i;
    if (r < N_) {
      float deg = 1.0f + (float)degL[i] * (1.0f / 16777216.0f);
      cnt[r] = (int)cntL[i];
      dinv[r] = rsqrtf(deg);
      sc[r] = 1.0f / deg;
    }
  }
}

// ---- exclusive scan over n1 = N+1 values (raw cnt, pad-free) ----
__global__ __launch_bounds__(256) void k_scan1(const int* __restrict__ cnt,
                                               int* __restrict__ out,
                                               int* __restrict__ bsums,
                                               int N_, int n1) {
  __shared__ int sm[256];
  const int t = threadIdx.x;
  const int base = blockIdx.x * 1024 + t * 4;
  int v[4], lsum = 0;
#pragma unroll
  for (int j = 0; j < 4; ++j) {
    int i = base + j;
    v[j] = (i < N_) ? cnt[i] : 0;
    lsum += v[j];
  }
  sm[t] = lsum;
  __syncthreads();
  for (int o = 1; o < 256; o <<= 1) {
    int x = (t >= o) ? sm[t - o] : 0;
    __syncthreads();
    if (t >= o) sm[t] += x;
    __syncthreads();
  }
  int run = sm[t] - lsum;
#pragma unroll
  for (int j = 0; j < 4; ++j) {
    int i = base + j;
    if (i < n1) out[i] = run;
    run += v[j];
  }
  if (t == 255) bsums[blockIdx.x] = sm[255];
}

__global__ __launch_bounds__(256) void k_scan2(int* __restrict__ bsums, int nb) {
  __shared__ int sm[256];
  int t = threadIdx.x;
  int v = (t < nb) ? bsums[t] : 0;
  sm[t] = v;
  __syncthreads();
  for (int o = 1; o < 256; o <<= 1) {
    int x = (t >= o) ? sm[t - o] : 0;
    __syncthreads();
    if (t >= o) sm[t] += x;
    __syncthreads();
  }
  if (t < nb) bsums[t] = sm[t] - v;
}

__global__ void k_scan3(int* __restrict__ out, const int* __restrict__ bsums, int n1) {
  int i = blockIdx.x * blockDim.x + threadIdx.x;
  if (i < n1) out[i] += bsums[i >> 10];
}

// Pass 2: one block per bucket; norm + CSR placement via LDS cursors.
__global__ __launch_bounds__(256) void k_fin(
    const unsigned long long* __restrict__ bstage, const int* __restrict__ rowstart,
    const unsigned* __restrict__ gcur0, const float* __restrict__ dinv,
    unsigned* __restrict__ elist, int N_) {
  __shared__ unsigned lcur[BROWS];
  __shared__ int rsL[BROWS];
  __shared__ float dvL[BROWS];
  const int b = blockIdx.x, t = threadIdx.x;
  const int r0 = b * BROWS;
  for (int i = t; i < BROWS; i += 256) {
    lcur[i] = 0;
    int r = r0 + i;
    dvL[i] = (r < N_) ? dinv[r] : 0.f;
    rsL[i] = (r < N_) ? rowstart[r] : 0;
  }
  __syncthreads();
  const unsigned beg = (unsigned)(b * CAP), end = gcur0[b];
  for (unsigned p = beg + t; p < end; p += 256) {
    unsigned long long v = bstage[p];
    unsigned hi = (unsigned)(v >> 32);
    unsigned r = hi >> 17;
    unsigned s = hi & 0x1FFFFu;
    float w = __uint_as_float((unsigned)v);
    float nm = w * dinv[s] * dvL[r];
    unsigned h15 = (unsigned)__half_as_ushort(__float2half(nm));
    unsigned slot = (unsigned)rsL[r] + atomicAdd(&lcur[r], 1u);
    elist[slot] = (h15 << 17) | s;
  }
}

// MFMA GEMM: 128x64/block, 4 waves x (32x64). 16B vector staging.
template <int KP, int FUSE>
__global__ __launch_bounds__(256) void k_gemm_mfma(
    const void* __restrict__ Ap, const unsigned short* __restrict__ wt,
    const float* __restrict__ bias, const float* __restrict__ stats,
    const float* __restrict__ gam, const float* __restrict__ bet,
    unsigned short* __restrict__ Hu, int n, int Kreal, float invN) {
  __shared__ unsigned short Ah[128 * KP];
  __shared__ unsigned short Bt[64 * KP];
  __shared__ float saL[DH], sbL[DH];
  const int tid = threadIdx.x;
  const int r0 = blockIdx.x * 128;
  if (FUSE) {
    if (tid < DH) {
      float mean = stats[tid] * invN;
      float var = stats[DH + tid] * invN - mean * mean;
      float a = rsqrtf(var + EPSV) * gam[tid];
      saL[tid] = a;
      sbL[tid] = bet[tid] - mean * a;
    }
    __syncthreads();
  }
  constexpr int KC = KP / 8;
  for (int ci = tid; ci < 128 * KC; ci += 256) {
    int row = ci / KC, kc = ci % KC, k0 = kc * 8;
    int gr = r0 + row;
    uint4 av = {0, 0, 0, 0};
    if (FUSE) {
      const unsigned short* Aa = (const unsigned short*)Ap;
      if (gr < n) av = *(const uint4*)&Aa[(size_t)gr * KP + k0];
      const unsigned short* ap = (const unsigned short*)&av;
      unsigned short ov[8];
#pragma unroll
      for (int j = 0; j < 8; ++j) {
        int k = k0 + j;
        float a = __half2float(__ushort_as_half(ap[j]));
        ov[j] = __half_as_ushort(__float2half(fmaxf(a * saL[k] + sbL[k], 0.f)));
      }
      av = *(uint4*)ov;
    } else {
      const float* Ax = (const float*)Ap;
      unsigned short ov[8] = {0, 0, 0, 0, 0, 0, 0, 0};
      if (gr < n) {
        if (k0 + 8 <= Kreal) {
          float4 a = *(const float4*)&Ax[(size_t)gr * Kreal + k0];
          float4 b = *(const float4*)&Ax[(size_t)gr * Kreal + k0 + 4];
          ov[0] = __half_as_ushort(__float2half(a.x));
          ov[1] = __half_as_ushort(__float2half(a.y));
          ov[2] = __half_as_ushort(__float2half(a.z));
          ov[3] = __half_as_ushort(__float2half(a.w));
          ov[4] = __half_as_ushort(__float2half(b.x));
          ov[5] = __half_as_ushort(__float2half(b.y));
          ov[6] = __half_as_ushort(__float2half(b.z));
          ov[7] = __half_as_ushort(__float2half(b.w));
        } else if (k0 < Kreal) {
#pragma unroll
          for (int j = 0; j < 8; ++j) {
            int k = k0 + j;
            if (k < Kreal)
              ov[j] = __half_as_ushort(__float2half(Ax[(size_t)gr * Kreal + k]));
          }
        }
      }
      av = *(uint4*)ov;
    }
    *(uint4*)&Ah[row * KP + (k0 ^ ((row & 7) * 8))] = av;
  }
  for (int ci = tid; ci < 64 * KC; ci += 256) {
    int c = ci / KC, kc = ci % KC, k0 = kc * 8;
    uint4 wv = *(const uint4*)&wt[c * KP + k0];
    *(uint4*)&Bt[c * KP + (k0 ^ ((c & 7) * 8))] = wv;
  }
  __syncthreads();
  const int w = tid >> 6, l = tid & 63;
  const int lr = l & 15, lg = l >> 4;
  f32x4 acc[2][4];
#pragma unroll
  for (int a1 = 0; a1 < 2; ++a1)
#pragma unroll
    for (int a2 = 0; a2 < 4; ++a2) acc[a1][a2] = (f32x4){0.f, 0.f, 0.f, 0.f};
#pragma unroll
  for (int ks = 0; ks < KP / 32; ++ks) {
    const int k0 = ks * 32 + lg * 8;
    half8 av[2], bv[4];
#pragma unroll
    for (int rf = 0; rf < 2; ++rf) {
      int row = w * 32 + rf * 16 + lr;
      av[rf] = *(const half8*)&Ah[row * KP + (k0 ^ ((row & 7) * 8))];
    }
#pragma unroll
    for (int cf = 0; cf < 4; ++cf) {
      int col = cf * 16 + lr;
      bv[cf] = *(const half8*)&Bt[col * KP + (k0 ^ ((col & 7) * 8))];
    }
#pragma unroll
    for (int rf = 0; rf < 2; ++rf)
#pragma unroll
      for (int cf = 0; cf < 4; ++cf)
        acc[rf][cf] =
            __builtin_amdgcn_mfma_f32_16x16x32_f16(av[rf], bv[cf], acc[rf][cf], 0, 0, 0);
  }
#pragma unroll
  for (int rf = 0; rf < 2; ++rf) {
#pragma unroll
    for (int cf = 0; cf < 4; ++cf) {
      int col = cf * 16 + lr;
      float bcol = bias[col];
#pragma unroll
      for (int i = 0; i < 4; ++i) {
        int row = r0 + w * 32 + rf * 16 + lg * 4 + i;
        if (row < n)
          Hu[(size_t)row * DH + col] = __half_as_ushort(__float2half(acc[rf][cf][i] + bcol));
      }
    }
  }
}

// Pull aggregation: one wave per dst row, lane d = feature d; pad-free with
// 16-deep in-flight gather batches (reg roundup: pad lanes eL=0 -> no-op FMA).
__global__ __launch_bounds__(256) void k_gather(
    const unsigned* __restrict__ elist, const int* __restrict__ rowstart,
    const unsigned short* __restrict__ Hu, const float* __restrict__ sc,
    unsigned short* __restrict__ AGGu, float* __restrict__ statp, int n) {
  const int wid = threadIdx.x >> 6;
  const int d = threadIdx.x & 63;
  const int gw = blockIdx.x * 4 + wid;
  const int nw = gridDim.x * 4;
  float s = 0.f, ss = 0.f;
  for (int row = gw; row < n; row += nw) {
    const int rs = rowstart[row], re = rowstart[row + 1];
    float acc = __half2float(__ushort_as_half(Hu[(size_t)row * DH + d])) * sc[row];
    for (int base = rs; base < re; base += 64) {
      const int rem = re - base;
      unsigned eL = 0u;
      if (d < rem) eL = __builtin_nontemporal_load(&elist[base + d]);
      const int m = rem < 64 ? ((rem + 15) & ~15) : 64;
      for (int j = 0; j < m; j += 16) {
        unsigned e[16];
        float v[16];
#pragma unroll
        for (int jj = 0; jj < 16; ++jj) e[jj] = __shfl(eL, j + jj, 64);
#pragma unroll
        for (int jj = 0; jj < 16; ++jj)
          v[jj] = __half2float(__ushort_as_half(Hu[(size_t)(e[jj] & 0x1FFFFu) * DH + d]));
#pragma unroll
        for (int jj = 0; jj < 16; ++jj) {
          float nm = __half2float(__ushort_as_half((unsigned short)(e[jj] >> 17)));
          acc = fmaf(nm, v[jj], acc);
        }
      }
    }
    __builtin_nontemporal_store(__half_as_ushort(__float2half(acc)),
                                &AGGu[(size_t)row * DH + d]);
    s += acc;
    ss += acc * acc;
  }
  __shared__ float sm[4][DH], sm2[4][DH];
  sm[wid][d] = s;
  sm2[wid][d] = ss;
  __syncthreads();
  if (threadIdx.x < DH) {
    float a = sm[0][d] + sm[1][d] + sm[2][d] + sm[3][d];
    float b = sm2[0][d] + sm2[1][d] + sm2[2][d] + sm2[3][d];
    __builtin_nontemporal_store(a, &statp[(size_t)blockIdx.x * 128 + d]);
    __builtin_nontemporal_store(b, &statp[(size_t)blockIdx.x * 128 + DH + d]);
  }
}

// reduce per-block stat partials: one block per stat entry (128 blocks)
__global__ __launch_bounds__(256) void k_redstats(const float* __restrict__ statp,
                                                  float* __restrict__ stats, int nblk) {
  const int t = blockIdx.x;
  float s = 0.f;
  for (int b = threadIdx.x; b < nblk; b += 256) s += statp[(size_t)b * 128 + t];
#pragma unroll
  for (int o = 32; o > 0; o >>= 1) s += __shfl_down(s, o, 64);
  __shared__ float sm[4];
  if ((threadIdx.x & 63) == 0) sm[threadIdx.x >> 6] = s;
  __syncthreads();
  if (threadIdx.x == 0) stats[t] = sm[0] + sm[1] + sm[2] + sm[3];
}

// fused BN+ReLU+mean-pool+head: one block per graph.
__global__ __launch_bounds__(256) void k_poolhead(
    const unsigned short* __restrict__ AGGu, const float* __restrict__ stats,
    const float* __restrict__ gam, const float* __restrict__ bet,
    const float* __restrict__ ow, const int* __restrict__ gstart,
    const float* __restrict__ ob, float* __restrict__ out, float invN) {
  const int g = blockIdx.x;
  const int gs = gstart[g], ge = gstart[g + 1];
  const int wid = threadIdx.x >> 6;
  const int d = threadIdx.x & 63;
  float mean = stats[d] * invN;
  float var = stats[DH + d] * invN - mean * mean;
  float sa = rsqrtf(var + EPSV) * gam[d];
  float sb = bet[d] - mean * sa;
  const float w = ow[d];
  float acc = 0.f;
  for (int row = gs + wid; row < ge; row += 4) {
    float v = __half2float(__ushort_as_half(AGGu[(size_t)row * DH + d]));
    acc += fmaxf(v * sa + sb, 0.f) * w;
  }
#pragma unroll
  for (int off = 32; off > 0; off >>= 1) acc += __shfl_down(acc, off, 64);
  __shared__ float sm[4];
  if (d == 0) sm[wid] = acc;
  __syncthreads();
  if (threadIdx.x == 0) {
    float s = sm[0] + sm[1] + sm[2] + sm[3];
    float cnt = (float)(ge - gs);
    out[g] = s / fmaxf(cnt, 1.0f) + ob[0];
  }
}

extern "C" void kernel_launch(void* const* d_in, const int* in_sizes, int n_in,
                              void* d_out, int out_size, void* d_ws, size_t ws_size,
                              hipStream_t stream) {
  const float* x    = (const float*)d_in[0];
  const int*   ei   = (const int*)d_in[1];
  const float* ew   = (const float*)d_in[2];
  const int*   batch= (const int*)d_in[3];
  const float* w0   = (const float*)d_in[4];
  const float* b0   = (const float*)d_in[5];
  const float* g0   = (const float*)d_in[6];
  const float* be0  = (const float*)d_in[7];
  const float* w1   = (const float*)d_in[8];
  const float* b1   = (const float*)d_in[9];
  const float* g1   = (const float*)d_in[10];
  const float* be1  = (const float*)d_in[11];
  const float* w2   = (const float*)d_in[12];
  const float* b2   = (const float*)d_in[13];
  const float* g2   = (const float*)d_in[14];
  const float* be2  = (const float*)d_in[15];
  const float* ow   = (const float*)d_in[16];
  const float* ob   = (const float*)d_in[17];

  const int N_  = in_sizes[3];
  const int E_  = in_sizes[2];
  const int DIN_= in_sizes[0] / N_;
  const int G_  = out_size;
  const int* srcIdx = ei;
  const int* dstIdx = ei + E_;
  const int n1 = N_ + 1;

  float* ws = (float*)d_ws;
  size_t off = 0;
  unsigned long long* bstage = (unsigned long long*)(ws + off);
  off += (size_t)2 * NBUK * CAP;
  unsigned* elist = (unsigned*)(ws + off); off += E_;
  float* dinv     = ws + off; off += N_;
  float* sc       = ws + off; off += N_;
  int*   cnt      = (int*)(ws + off); off += N_;
  int*   rowstart = (int*)(ws + off); off += n1 + 1;
  int*   bsums    = (int*)(ws + off); off += 256;
  unsigned* gcur0 = (unsigned*)(ws + off); off += NBUK;
  int*   gstart   = (int*)(ws + off); off += G_ + 1;
  unsigned short* hbuf = (unsigned short*)(ws + off); off += (size_t)N_ * 32;
  unsigned short* aggb = (unsigned short*)(ws + off); off += (size_t)N_ * 32;
  unsigned short* wt0 = (unsigned short*)(ws + off); off += 64 * 128 / 2;
  unsigned short* wt1 = (unsigned short*)(ws + off); off += 64 * 64 / 2;
  unsigned short* wt2 = (unsigned short*)(ws + off); off += 64 * 64 / 2;
  float* stats    = ws + off; off += 2 * DH;
  float* statp    = ws + off; off += (size_t)GBLK * 128;
  (void)ws_size; (void)n_in;

  // --- combined setup (gbound + gcur0 + W transposes) ---
  const int nbN = (N_ + 255) / 256;
  const int wtBlocks = (64 * 128 + 2 * 64 * 64 + 255) / 256;
  k_setup<<<nbN + 1 + wtBlocks, 256, 0, stream>>>(
      batch, gstart, gcur0, w0, w1, w2, wt0, wt1, wt2, N_, G_, DIN_, nbN);

  // --- binned CSR build (pad-free) ---
  k_bin0<<<(E_ + 256 * BINJ - 1) / (256 * BINJ), 256, 0, stream>>>(
      srcIdx, dstIdx, ew, gcur0, bstage, E_);
  k_bcnt<<<NBUK, 256, 0, stream>>>(bstage, gcur0, cnt, dinv, sc, N_);

  const int nb = (n1 + 1023) / 1024;
  k_scan1<<<nb, 256, 0, stream>>>(cnt, rowstart, bsums, N_, n1);
  k_scan2<<<1, 256, 0, stream>>>(bsums, nb);
  k_scan3<<<(n1 + 255) / 256, 256, 0, stream>>>(rowstart, bsums, n1);

  k_fin<<<NBUK, 256, 0, stream>>>(bstage, rowstart, gcur0, dinv, elist, N_);

  const float* Bl[3]  = {b0, b1, b2};
  const float* Gl[3]  = {g0, g1, g2};
  const float* BeL[3] = {be0, be1, be2};
  const unsigned short* Wt[3] = {wt0, wt1, wt2};

  const float invN = 1.0f / (float)N_;
  const int gblk = (N_ + 127) / 128;

  for (int l = 0; l < 3; ++l) {
    if (l == 0) {
      k_gemm_mfma<128, 0><<<gblk, 256, 0, stream>>>(
          (const void*)x, Wt[0], Bl[0], stats, nullptr, nullptr, hbuf, N_, DIN_, invN);
    } else {
      k_gemm_mfma<64, 1><<<gblk, 256, 0, stream>>>(
          (const void*)aggb, Wt[l], Bl[l], stats, Gl[l - 1], BeL[l - 1], hbuf, N_, DH, invN);
    }
    k_gather<<<GBLK, 256, 0, stream>>>(elist, rowstart, hbuf, sc, aggb, statp, N_);
    k_redstats<<<128, 256, 0, stream>>>(statp, stats, GBLK);
  }

  // --- fused BN2+ReLU+pooling+head ---
  k_poolhead<<<G_, 256, 0, stream>>>(aggb, stats, g2, be2, ow, gstart, ob,
                                     (float*)d_out, invN);
}

// Round 18
// 326.352 us; speedup vs baseline: 1.0167x; 1.0167x over previous
//
#include <hip/hip_runtime.h>
#include <hip/hip_fp16.h>
#include <cstdint>

#define DH 64
#define EPSV 1e-5f
#define GBLK 2048
#define NBUK 256
#define BROWS 512
#define BINJ 8
#define CAP 12288

typedef _Float16 half8 __attribute__((ext_vector_type(8)));
typedef float f32x4 __attribute__((ext_vector_type(4)));

// Combined setup: graph boundaries + bucket cursors + 3x W transpose->fp16
__global__ __launch_bounds__(256) void k_setup(
    const int* __restrict__ batch, int* __restrict__ gstart,
    unsigned* __restrict__ gcur0,
    const float* __restrict__ w0, const float* __restrict__ w1,
    const float* __restrict__ w2, unsigned short* __restrict__ wt0,
    unsigned short* __restrict__ wt1, unsigned short* __restrict__ wt2,
    int N_, int G_, int DIN_, int nbN) {
  const int b = blockIdx.x, t = threadIdx.x;
  if (b < nbN) {
    int i = b * 256 + t;
    if (i >= N_) return;
    int bb = batch[i];
    if (i == 0) {
      for (int g = 0; g <= bb; ++g) gstart[g] = 0;
    }
    int nb2 = (i + 1 < N_) ? batch[i + 1] : G_;
    for (int g = bb + 1; g <= nb2; ++g) gstart[g] = i + 1;
  } else if (b == nbN) {
    if (t < NBUK) gcur0[t] = (unsigned)(t * CAP);
  } else {
    int idx = (b - nbN - 1) * 256 + t;
    if (idx < 64 * 128) {
      int c = idx / 128, k = idx % 128;
      wt0[idx] = __half_as_ushort(__float2half(k < DIN_ ? w0[k * DH + c] : 0.f));
    } else if (idx < 64 * 128 + 64 * 64) {
      int l2 = idx - 64 * 128;
      int c = l2 / 64, k = l2 % 64;
      wt1[l2] = __half_as_ushort(__float2half(w1[k * DH + c]));
    } else if (idx < 64 * 128 + 2 * 64 * 64) {
      int l2 = idx - 64 * 128 - 64 * 64;
      int c = l2 / 64, k = l2 % 64;
      wt2[l2] = __half_as_ushort(__float2half(w2[k * DH + c]));
    }
  }
}

// Pass 1: bin edges by dst bucket. payload: hi=(dst&511)<<17|src, lo=fp32 ew.
__global__ __launch_bounds__(256) void k_bin0(
    const int* __restrict__ src, const int* __restrict__ dst,
    const float* __restrict__ ew, unsigned* __restrict__ gcur0,
    unsigned long long* __restrict__ bstage, int E_) {
  __shared__ unsigned cntL[NBUK], offL[NBUK], runL[NBUK];
  const int t = threadIdx.x;
  const int base = blockIdx.x * (256 * BINJ);
  cntL[t] = 0;
  runL[t] = 0;
  __syncthreads();
  unsigned hi[BINJ], lo[BINJ];
  int bb[BINJ];
#pragma unroll
  for (int j = 0; j < BINJ; ++j) {
    int e = base + j * 256 + t;
    bb[j] = -1;
    if (e < E_) {
      int q = dst[e];
      hi[j] = ((unsigned)(q & (BROWS - 1)) << 17) | (unsigned)src[e];
      lo[j] = __float_as_uint(ew[e]);
      bb[j] = q >> 9;
      atomicAdd(&cntL[bb[j]], 1u);
    }
  }
  __syncthreads();
  offL[t] = cntL[t] ? atomicAdd(&gcur0[t], cntL[t]) : 0u;
  __syncthreads();
#pragma unroll
  for (int j = 0; j < BINJ; ++j) {
    if (bb[j] >= 0) {
      unsigned p = offL[bb[j]] + atomicAdd(&runL[bb[j]], 1u);
      bstage[p] = ((unsigned long long)hi[j] << 32) | lo[j];
    }
  }
}

// Per-bucket histogram from staged runs (deterministic fixed-point sum).
__global__ __launch_bounds__(256) void k_bcnt(
    const unsigned long long* __restrict__ bstage, const unsigned* __restrict__ gcur0,
    int* __restrict__ cnt, float* __restrict__ dinv, float* __restrict__ sc, int N_) {
  __shared__ unsigned cntL[BROWS], degL[BROWS];
  const int b = blockIdx.x, t = threadIdx.x;
  for (int i = t; i < BROWS; i += 256) {
    cntL[i] = 0;
    degL[i] = 0;
  }
  __syncthreads();
  const unsigned beg = (unsigned)(b * CAP), end = gcur0[b];
  for (unsigned p = beg + t; p < end; p += 256) {
    unsigned long long v = bstage[p];
    unsigned r = (unsigned)(v >> 49);
    float w = __uint_as_float((unsigned)v);
    atomicAdd(&cntL[r], 1u);
    atomicAdd(&degL[r], (unsigned)(w * 16777216.0f));
  }
  __syncthreads();
  for (int i = t; i < BROWS; i += 256) {
    int r = b * BROWS + i;
    if (r < N_) {
      float deg = 1.0f + (float)degL[i] * (1.0f / 16777216.0f);
      cnt[r] = (int)cntL[i];
      dinv[r] = rsqrtf(deg);
      sc[r] = 1.0f / deg;
    }
  }
}

// ---- exclusive scan over n1 = N+1 values (raw cnt, pad-free) ----
__global__ __launch_bounds__(256) void k_scan1(const int* __restrict__ cnt,
                                               int* __restrict__ out,
                                               int* __restrict__ bsums,
                                               int N_, int n1) {
  __shared__ int sm[256];
  const int t = threadIdx.x;
  const int base = blockIdx.x * 1024 + t * 4;
  int v[4], lsum = 0;
#pragma unroll
  for (int j = 0; j < 4; ++j) {
    int i = base + j;
    v[j] = (i < N_) ? cnt[i] : 0;
    lsum += v[j];
  }
  sm[t] = lsum;
  __syncthreads();
  for (int o = 1; o < 256; o <<= 1) {
    int x = (t >= o) ? sm[t - o] : 0;
    __syncthreads();
    if (t >= o) sm[t] += x;
    __syncthreads();
  }
  int run = sm[t] - lsum;
#pragma unroll
  for (int j = 0; j < 4; ++j) {
    int i = base + j;
    if (i < n1) out[i] = run;
    run += v[j];
  }
  if (t == 255) bsums[blockIdx.x] = sm[255];
}

__global__ __launch_bounds__(256) void k_scan2(int* __restrict__ bsums, int nb) {
  __shared__ int sm[256];
  int t = threadIdx.x;
  int v = (t < nb) ? bsums[t] : 0;
  sm[t] = v;
  __syncthreads();
  for (int o = 1; o < 256; o <<= 1) {
    int x = (t >= o) ? sm[t - o] : 0;
    __syncthreads();
    if (t >= o) sm[t] += x;
    __syncthreads();
  }
  if (t < nb) bsums[t] = sm[t] - v;
}

__global__ void k_scan3(int* __restrict__ out, const int* __restrict__ bsums, int n1) {
  int i = blockIdx.x * blockDim.x + threadIdx.x;
  if (i < n1) out[i] += bsums[i >> 10];
}

// Pass 2: one block per bucket; norm + CSR placement via LDS cursors.
__global__ __launch_bounds__(256) void k_fin(
    const unsigned long long* __restrict__ bstage, const int* __restrict__ rowstart,
    const unsigned* __restrict__ gcur0, const float* __restrict__ dinv,
    unsigned* __restrict__ elist, int N_) {
  __shared__ unsigned lcur[BROWS];
  __shared__ int rsL[BROWS];
  __shared__ float dvL[BROWS];
  const int b = blockIdx.x, t = threadIdx.x;
  const int r0 = b * BROWS;
  for (int i = t; i < BROWS; i += 256) {
    lcur[i] = 0;
    int r = r0 + i;
    dvL[i] = (r < N_) ? dinv[r] : 0.f;
    rsL[i] = (r < N_) ? rowstart[r] : 0;
  }
  __syncthreads();
  const unsigned beg = (unsigned)(b * CAP), end = gcur0[b];
  for (unsigned p = beg + t; p < end; p += 256) {
    unsigned long long v = bstage[p];
    unsigned hi = (unsigned)(v >> 32);
    unsigned r = hi >> 17;
    unsigned s = hi & 0x1FFFFu;
    float w = __uint_as_float((unsigned)v);
    float nm = w * dinv[s] * dvL[r];
    unsigned h15 = (unsigned)__half_as_ushort(__float2half(nm));
    unsigned slot = (unsigned)rsL[r] + atomicAdd(&lcur[r], 1u);
    elist[slot] = (h15 << 17) | s;
  }
}

// MFMA GEMM: 128x64/block, 4 waves x (32x64). 16B vector staging.
template <int KP, int FUSE>
__global__ __launch_bounds__(256) void k_gemm_mfma(
    const void* __restrict__ Ap, const unsigned short* __restrict__ wt,
    const float* __restrict__ bias, const float* __restrict__ stats,
    const float* __restrict__ gam, const float* __restrict__ bet,
    unsigned short* __restrict__ Hu, int n, int Kreal, float invN) {
  __shared__ unsigned short Ah[128 * KP];
  __shared__ unsigned short Bt[64 * KP];
  __shared__ float saL[DH], sbL[DH];
  const int tid = threadIdx.x;
  const int r0 = blockIdx.x * 128;
  if (FUSE) {
    if (tid < DH) {
      float mean = stats[tid] * invN;
      float var = stats[DH + tid] * invN - mean * mean;
      float a = rsqrtf(var + EPSV) * gam[tid];
      saL[tid] = a;
      sbL[tid] = bet[tid] - mean * a;
    }
    __syncthreads();
  }
  constexpr int KC = KP / 8;
  for (int ci = tid; ci < 128 * KC; ci += 256) {
    int row = ci / KC, kc = ci % KC, k0 = kc * 8;
    int gr = r0 + row;
    uint4 av = {0, 0, 0, 0};
    if (FUSE) {
      const unsigned short* Aa = (const unsigned short*)Ap;
      if (gr < n) av = *(const uint4*)&Aa[(size_t)gr * KP + k0];
      const unsigned short* ap = (const unsigned short*)&av;
      unsigned short ov[8];
#pragma unroll
      for (int j = 0; j < 8; ++j) {
        int k = k0 + j;
        float a = __half2float(__ushort_as_half(ap[j]));
        ov[j] = __half_as_ushort(__float2half(fmaxf(a * saL[k] + sbL[k], 0.f)));
      }
      av = *(uint4*)ov;
    } else {
      const float* Ax = (const float*)Ap;
      unsigned short ov[8] = {0, 0, 0, 0, 0, 0, 0, 0};
      if (gr < n) {
        if (k0 + 8 <= Kreal) {
          float4 a = *(const float4*)&Ax[(size_t)gr * Kreal + k0];
          float4 b = *(const float4*)&Ax[(size_t)gr * Kreal + k0 + 4];
          ov[0] = __half_as_ushort(__float2half(a.x));
          ov[1] = __half_as_ushort(__float2half(a.y));
          ov[2] = __half_as_ushort(__float2half(a.z));
          ov[3] = __half_as_ushort(__float2half(a.w));
          ov[4] = __half_as_ushort(__float2half(b.x));
          ov[5] = __half_as_ushort(__float2half(b.y));
          ov[6] = __half_as_ushort(__float2half(b.z));
          ov[7] = __half_as_ushort(__float2half(b.w));
        } else if (k0 < Kreal) {
#pragma unroll
          for (int j = 0; j < 8; ++j) {
            int k = k0 + j;
            if (k < Kreal)
              ov[j] = __half_as_ushort(__float2half(Ax[(size_t)gr * Kreal + k]));
          }
        }
      }
      av = *(uint4*)ov;
    }
    *(uint4*)&Ah[row * KP + (k0 ^ ((row & 7) * 8))] = av;
  }
  for (int ci = tid; ci < 64 * KC; ci += 256) {
    int c = ci / KC, kc = ci % KC, k0 = kc * 8;
    uint4 wv = *(const uint4*)&wt[c * KP + k0];
    *(uint4*)&Bt[c * KP + (k0 ^ ((c & 7) * 8))] = wv;
  }
  __syncthreads();
  const int w = tid >> 6, l = tid & 63;
  const int lr = l & 15, lg = l >> 4;
  f32x4 acc[2][4];
#pragma unroll
  for (int a1 = 0; a1 < 2; ++a1)
#pragma unroll
    for (int a2 = 0; a2 < 4; ++a2) acc[a1][a2] = (f32x4){0.f, 0.f, 0.f, 0.f};
#pragma unroll
  for (int ks = 0; ks < KP / 32; ++ks) {
    const int k0 = ks * 32 + lg * 8;
    half8 av[2], bv[4];
#pragma unroll
    for (int rf = 0; rf < 2; ++rf) {
      int row = w * 32 + rf * 16 + lr;
      av[rf] = *(const half8*)&Ah[row * KP + (k0 ^ ((row & 7) * 8))];
    }
#pragma unroll
    for (int cf = 0; cf < 4; ++cf) {
      int col = cf * 16 + lr;
      bv[cf] = *(const half8*)&Bt[col * KP + (k0 ^ ((col & 7) * 8))];
    }
#pragma unroll
    for (int rf = 0; rf < 2; ++rf)
#pragma unroll
      for (int cf = 0; cf < 4; ++cf)
        acc[rf][cf] =
            __builtin_amdgcn_mfma_f32_16x16x32_f16(av[rf], bv[cf], acc[rf][cf], 0, 0, 0);
  }
#pragma unroll
  for (int rf = 0; rf < 2; ++rf) {
#pragma unroll
    for (int cf = 0; cf < 4; ++cf) {
      int col = cf * 16 + lr;
      float bcol = bias[col];
#pragma unroll
      for (int i = 0; i < 4; ++i) {
        int row = r0 + w * 32 + rf * 16 + lg * 4 + i;
        if (row < n)
          Hu[(size_t)row * DH + col] = __half_as_ushort(__float2half(acc[rf][cf][i] + bcol));
      }
    }
  }
}

// Pull aggregation: one wave per dst row, lane d = feature d; pad-free
// (register roundup: lanes >= rem stage eL=0 -> norm 0 no-op FMAs).
__global__ __launch_bounds__(256) void k_gather(
    const unsigned* __restrict__ elist, const int* __restrict__ rowstart,
    const unsigned short* __restrict__ Hu, const float* __restrict__ sc,
    unsigned short* __restrict__ AGGu, float* __restrict__ statp, int n) {
  const int wid = threadIdx.x >> 6;
  const int d = threadIdx.x & 63;
  const int gw = blockIdx.x * 4 + wid;
  const int nw = gridDim.x * 4;
  float s = 0.f, ss = 0.f;
  for (int row = gw; row < n; row += nw) {
    const int rs = rowstart[row], re = rowstart[row + 1];
    float acc = __half2float(__ushort_as_half(Hu[(size_t)row * DH + d])) * sc[row];
    for (int base = rs; base < re; base += 64) {
      const int rem = re - base;
      unsigned eL = 0u;
      if (d < rem) eL = __builtin_nontemporal_load(&elist[base + d]);
      const int m = rem < 64 ? ((rem + 7) & ~7) : 64;
      for (int j = 0; j < m; j += 8) {
        unsigned e[8];
        float v[8];
#pragma unroll
        for (int jj = 0; jj < 8; ++jj) e[jj] = __shfl(eL, j + jj, 64);
#pragma unroll
        for (int jj = 0; jj < 8; ++jj)
          v[jj] = __half2float(__ushort_as_half(Hu[(size_t)(e[jj] & 0x1FFFFu) * DH + d]));
#pragma unroll
        for (int jj = 0; jj < 8; ++jj) {
          float nm = __half2float(__ushort_as_half((unsigned short)(e[jj] >> 17)));
          acc = fmaf(nm, v[jj], acc);
        }
      }
    }
    __builtin_nontemporal_store(__half_as_ushort(__float2half(acc)),
                                &AGGu[(size_t)row * DH + d]);
    s += acc;
    ss += acc * acc;
  }
  __shared__ float sm[4][DH], sm2[4][DH];
  sm[wid][d] = s;
  sm2[wid][d] = ss;
  __syncthreads();
  if (threadIdx.x < DH) {
    float a = sm[0][d] + sm[1][d] + sm[2][d] + sm[3][d];
    float b = sm2[0][d] + sm2[1][d] + sm2[2][d] + sm2[3][d];
    __builtin_nontemporal_store(a, &statp[(size_t)blockIdx.x * 128 + d]);
    __builtin_nontemporal_store(b, &statp[(size_t)blockIdx.x * 128 + DH + d]);
  }
}

// reduce per-block stat partials: one block per stat entry (128 blocks)
__global__ __launch_bounds__(256) void k_redstats(const float* __restrict__ statp,
                                                  float* __restrict__ stats, int nblk) {
  const int t = blockIdx.x;
  float s = 0.f;
  for (int b = threadIdx.x; b < nblk; b += 256) s += statp[(size_t)b * 128 + t];
#pragma unroll
  for (int o = 32; o > 0; o >>= 1) s += __shfl_down(s, o, 64);
  __shared__ float sm[4];
  if ((threadIdx.x & 63) == 0) sm[threadIdx.x >> 6] = s;
  __syncthreads();
  if (threadIdx.x == 0) stats[t] = sm[0] + sm[1] + sm[2] + sm[3];
}

// fused BN+ReLU+mean-pool+head: one block per graph.
__global__ __launch_bounds__(256) void k_poolhead(
    const unsigned short* __restrict__ AGGu, const float* __restrict__ stats,
    const float* __restrict__ gam, const float* __restrict__ bet,
    const float* __restrict__ ow, const int* __restrict__ gstart,
    const float* __restrict__ ob, float* __restrict__ out, float invN) {
  const int g = blockIdx.x;
  const int gs = gstart[g], ge = gstart[g + 1];
  const int wid = threadIdx.x >> 6;
  const int d = threadIdx.x & 63;
  float mean = stats[d] * invN;
  float var = stats[DH + d] * invN - mean * mean;
  float sa = rsqrtf(var + EPSV) * gam[d];
  float sb = bet[d] - mean * sa;
  const float w = ow[d];
  float acc = 0.f;
  for (int row = gs + wid; row < ge; row += 4) {
    float v = __half2float(__ushort_as_half(AGGu[(size_t)row * DH + d]));
    acc += fmaxf(v * sa + sb, 0.f) * w;
  }
#pragma unroll
  for (int off = 32; off > 0; off >>= 1) acc += __shfl_down(acc, off, 64);
  __shared__ float sm[4];
  if (d == 0) sm[wid] = acc;
  __syncthreads();
  if (threadIdx.x == 0) {
    float s = sm[0] + sm[1] + sm[2] + sm[3];
    float cnt = (float)(ge - gs);
    out[g] = s / fmaxf(cnt, 1.0f) + ob[0];
  }
}

extern "C" void kernel_launch(void* const* d_in, const int* in_sizes, int n_in,
                              void* d_out, int out_size, void* d_ws, size_t ws_size,
                              hipStream_t stream) {
  const float* x    = (const float*)d_in[0];
  const int*   ei   = (const int*)d_in[1];
  const float* ew   = (const float*)d_in[2];
  const int*   batch= (const int*)d_in[3];
  const float* w0   = (const float*)d_in[4];
  const float* b0   = (const float*)d_in[5];
  const float* g0   = (const float*)d_in[6];
  const float* be0  = (const float*)d_in[7];
  const float* w1   = (const float*)d_in[8];
  const float* b1   = (const float*)d_in[9];
  const float* g1   = (const float*)d_in[10];
  const float* be1  = (const float*)d_in[11];
  const float* w2   = (const float*)d_in[12];
  const float* b2   = (const float*)d_in[13];
  const float* g2   = (const float*)d_in[14];
  const float* be2  = (const float*)d_in[15];
  const float* ow   = (const float*)d_in[16];
  const float* ob   = (const float*)d_in[17];

  const int N_  = in_sizes[3];
  const int E_  = in_sizes[2];
  const int DIN_= in_sizes[0] / N_;
  const int G_  = out_size;
  const int* srcIdx = ei;
  const int* dstIdx = ei + E_;
  const int n1 = N_ + 1;

  float* ws = (float*)d_ws;
  size_t off = 0;
  unsigned long long* bstage = (unsigned long long*)(ws + off);
  off += (size_t)2 * NBUK * CAP;
  unsigned* elist = (unsigned*)(ws + off); off += E_;
  float* dinv     = ws + off; off += N_;
  float* sc       = ws + off; off += N_;
  int*   cnt      = (int*)(ws + off); off += N_;
  int*   rowstart = (int*)(ws + off); off += n1 + 1;
  int*   bsums    = (int*)(ws + off); off += 256;
  unsigned* gcur0 = (unsigned*)(ws + off); off += NBUK;
  int*   gstart   = (int*)(ws + off); off += G_ + 1;
  unsigned short* hbuf = (unsigned short*)(ws + off); off += (size_t)N_ * 32;
  unsigned short* aggb = (unsigned short*)(ws + off); off += (size_t)N_ * 32;
  unsigned short* wt0 = (unsigned short*)(ws + off); off += 64 * 128 / 2;
  unsigned short* wt1 = (unsigned short*)(ws + off); off += 64 * 64 / 2;
  unsigned short* wt2 = (unsigned short*)(ws + off); off += 64 * 64 / 2;
  float* stats    = ws + off; off += 2 * DH;
  float* statp    = ws + off; off += (size_t)GBLK * 128;
  (void)ws_size; (void)n_in;

  // --- combined setup (gbound + gcur0 + W transposes) ---
  const int nbN = (N_ + 255) / 256;
  const int wtBlocks = (64 * 128 + 2 * 64 * 64 + 255) / 256;
  k_setup<<<nbN + 1 + wtBlocks, 256, 0, stream>>>(
      batch, gstart, gcur0, w0, w1, w2, wt0, wt1, wt2, N_, G_, DIN_, nbN);

  // --- binned CSR build (pad-free) ---
  k_bin0<<<(E_ + 256 * BINJ - 1) / (256 * BINJ), 256, 0, stream>>>(
      srcIdx, dstIdx, ew, gcur0, bstage, E_);
  k_bcnt<<<NBUK, 256, 0, stream>>>(bstage, gcur0, cnt, dinv, sc, N_);

  const int nb = (n1 + 1023) / 1024;
  k_scan1<<<nb, 256, 0, stream>>>(cnt, rowstart, bsums, N_, n1);
  k_scan2<<<1, 256, 0, stream>>>(bsums, nb);
  k_scan3<<<(n1 + 255) / 256, 256, 0, stream>>>(rowstart, bsums, n1);

  k_fin<<<NBUK, 256, 0, stream>>>(bstage, rowstart, gcur0, dinv, elist, N_);

  const float* Bl[3]  = {b0, b1, b2};
  const float* Gl[3]  = {g0, g1, g2};
  const float* BeL[3] = {be0, be1, be2};
  const unsigned short* Wt[3] = {wt0, wt1, wt2};

  const float invN = 1.0f / (float)N_;
  const int gblk = (N_ + 127) / 128;

  for (int l = 0; l < 3; ++l) {
    if (l == 0) {
      k_gemm_mfma<128, 0><<<gblk, 256, 0, stream>>>(
          (const void*)x, Wt[0], Bl[0], stats, nullptr, nullptr, hbuf, N_, DIN_, invN);
    } else {
      k_gemm_mfma<64, 1><<<gblk, 256, 0, stream>>>(
          (const void*)aggb, Wt[l], Bl[l], stats, Gl[l - 1], BeL[l - 1], hbuf, N_, DH, invN);
    }
    k_gather<<<GBLK, 256, 0, stream>>>(elist, rowstart, hbuf, sc, aggb, statp, N_);
    k_redstats<<<128, 256, 0, stream>>>(statp, stats, GBLK);
  }

  // --- fused BN2+ReLU+pooling+head ---
  k_poolhead<<<G_, 256, 0, stream>>>(aggb, stats, g2, be2, ow, gstart, ob,
                                     (float*)d_out, invN);
}